// Round 1
// baseline (70.000 us; speedup 1.0000x reference)
//
#include <hip/hip_runtime.h>

// Analytic collapse (verified R1-R11, absmax 9.8e-4):
//   <Z_0> = c1*...*c7,  <Z_j> = c0*...*cj,  c_j = cos(t_j + theta_j)
// R13: latency restructure. 512 blocks x 256 thr, 16 tokens/block ->
// 2 independent blocks/CU (barrier decoupling). W and x go global->reg
// as MFMA fragments (rows are contiguous 32B chunks; W is 64KB, L2-hot
// across all 512 blocks) -- no LDS staging, no B1 barrier. LDS is only
// the cross-wave structures: sP (z values) + sS (scrambled attn out),
// 17.7 KB total. Split-bf16 scheme kept (hh+hl+lh MFMAs) but with a
// cheap split: round-half-up hi, exact residual, TRUNCATED lo, v_perm
// packing (~4 ops/float vs ~11). Error 2^-15 rel vs 2^-16 -- well inside
// the 9.26e-3 absmax budget (current 9.8e-4).
//  P1: 12 (mat,ntile) jobs, 3/wave: 6 MFMA + cos + DPP scan -> sP.
//  P2 (waves 0-1): row-per-lane attention, 8 tok/wave; writes scrambled
//      rows as split-bf16 into sS.
//  P3: 4 ntile jobs, 1/wave: 6 MFMA vs reg-resident Wo frags, direct store.

typedef float  f32x4  __attribute__((ext_vector_type(4)));
typedef short  bf16x8 __attribute__((ext_vector_type(8)));
typedef unsigned short u16;
typedef unsigned int   u32;

#define WRS 72   // shorts per sS row (64 data + 8 pad) = 144 B
#define SPS 68   // sP row stride (dwords), 16B-aligned

// d *= dpp_row_shr<sh>(d) gated to lanes with (lane&7) >= sh
#define DPP_SHR_STEP(d, j, sh)                                                 \
    {                                                                          \
        float _t = __int_as_float(__builtin_amdgcn_update_dpp(                 \
            0x3f800000, __float_as_int(d), 0x110 + sh, 0xf, 0xf, false));      \
        d *= ((j) >= (sh)) ? _t : 1.0f;                                        \
    }

// split f = hi + lo: hi = round-half-up bf16 (|r| <= 0.5 ulp), lo = trunc
// bf16 of exact residual -> total rel err <= 2^-15. Packs pairs via v_perm.
__device__ __forceinline__ void bfsplit2(float f0, float f1, u32& hh, u32& ll) {
    const u32 u0 = __float_as_uint(f0), u1 = __float_as_uint(f1);
    const u32 h0 = (u0 + 0x8000u) & 0xffff0000u;
    const u32 h1 = (u1 + 0x8000u) & 0xffff0000u;
    const float r0 = f0 - __uint_as_float(h0);            // exact
    const float r1 = f1 - __uint_as_float(h1);            // exact
    hh = __builtin_amdgcn_perm(h1, h0, 0x07060302u);      // [h1.hi16, h0.hi16]
    ll = __builtin_amdgcn_perm(__float_as_uint(r1), __float_as_uint(r0),
                               0x07060302u);
}

// 8 consecutive floats -> one hi frag + one lo frag (k-order preserved)
__device__ __forceinline__ void cvt8(const float4 v0, const float4 v1,
                                     bf16x8& hi, bf16x8& lo) {
    union { bf16x8 v; u32 u[4]; } H, L;
    bfsplit2(v0.x, v0.y, H.u[0], L.u[0]);
    bfsplit2(v0.z, v0.w, H.u[1], L.u[1]);
    bfsplit2(v1.x, v1.y, H.u[2], L.u[2]);
    bfsplit2(v1.z, v1.w, H.u[3], L.u[3]);
    hi = H.v; lo = L.v;
}

#define MFMA3(acc, ah, al, bh, bl)                                             \
    acc = __builtin_amdgcn_mfma_f32_16x16x32_bf16(al, bh, acc, 0, 0, 0);       \
    acc = __builtin_amdgcn_mfma_f32_16x16x32_bf16(ah, bl, acc, 0, 0, 0);       \
    acc = __builtin_amdgcn_mfma_f32_16x16x32_bf16(ah, bh, acc, 0, 0, 0);

__global__ __launch_bounds__(256, 2)
void qattn_fused(const float* __restrict__ xg,
                 const float* __restrict__ wqg, const float* __restrict__ wkg,
                 const float* __restrict__ wvg, const float* __restrict__ wog,
                 const float* __restrict__ thg,
                 float* __restrict__ outg)
{
    __shared__ __align__(16) float sP[48 * SPS];   // 13.1 KB  z values [m*16+t][e]
    __shared__ __align__(16) u16 sSh[16 * WRS];    // 2.3 KB   scr hi [rho][col]
    __shared__ __align__(16) u16 sSl[16 * WRS];    // 2.3 KB   scr lo

    const int tid  = threadIdx.x;
    const int lane = tid & 63;
    const int wg   = tid >> 6;         // 0..3
    const int l15  = lane & 15;
    const int quad = lane >> 4;
    const int j    = lane & 7;
    const int b    = blockIdx.x >> 5;  // batch
    const int g16  = blockIdx.x & 31;  // 16-token group in batch row

    // ---- x A-frags straight to registers: token row l15, cols quad*8(+32) ----
    const float* xr = xg + ((size_t)(b * 512 + g16 * 16 + l15) * 64) + quad * 8;
    bf16x8 ah0, al0, ah1, al1;
    cvt8(*(const float4*)xr, *(const float4*)(xr + 4), ah0, al0);
    cvt8(*(const float4*)(xr + 32), *(const float4*)(xr + 36), ah1, al1);
    const float thf = thg[j];

    // ---- P1: projections via MFMA; 3 (mat,ntile) jobs per wave ----
    #pragma unroll
    for (int ia = 0; ia < 3; ++ia) {
        const int aid = wg * 3 + ia;                 // 0..11
        const int m = aid >> 2, nt = aid & 3;        // m: 0=q 1=k 2=v
        const float* wm = (m == 0) ? wqg : ((m == 1) ? wkg : wvg);
        const float* wr = wm + (nt * 16 + l15) * 64 + quad * 8;
        bf16x8 bh0, bl0, bh1, bl1;
        cvt8(*(const float4*)wr, *(const float4*)(wr + 4), bh0, bl0);
        cvt8(*(const float4*)(wr + 32), *(const float4*)(wr + 36), bh1, bl1);
        f32x4 acc = {0.f, 0.f, 0.f, 0.f};
        MFMA3(acc, ah0, al0, bh0, bl0)               // k = 0..31
        MFMA3(acc, ah1, al1, bh1, bl1)               // k = 32..63
        // epilogue: lane holds t[token][e] for 4 tokens; e = nt*16 + l15
        #pragma unroll
        for (int r = 0; r < 4; ++r) {
            const float c = __cosf(acc[r] + thf);
            float d = c;                             // inclusive scan (c0..cj)
            DPP_SHR_STEP(d, j, 1)
            DPP_SHR_STEP(d, j, 2)
            DPP_SHR_STEP(d, j, 4)
            float ex = (j == 0) ? 1.0f : c;          // scan excluding c0
            DPP_SHR_STEP(ex, j, 1)
            DPP_SHR_STEP(ex, j, 2)
            DPP_SHR_STEP(ex, j, 4)
            const int base = (m * 16 + quad * 4 + r) * SPS + nt * 16 + l15;
            if (j > 0)  sP[base]     = d;            // z_j = c0..cj
            if (j == 7) sP[base - 7] = ex;           // z_0 = c1..c7 -> slot 0
        }
    }

    // ---- Wo B-frag preload (nt2 = wg) while sP settles ----
    const float* wor = wog + (wg * 16 + l15) * 64 + quad * 8;
    bf16x8 obh0, obl0, obh1, obl1;
    cvt8(*(const float4*)wor, *(const float4*)(wor + 4), obh0, obl0);
    cvt8(*(const float4*)(wor + 32), *(const float4*)(wor + 36), obh1, obl1);

    __syncthreads();                                 // B2: z ready

    // ---- P2 (waves 0-1): row-per-lane attention, 8 tokens/wave ----
    if (wg < 2) {
        const int tg = wg * 8 + (lane >> 3);         // block-local token 0..15
        const int i  = j;                            // head (score row)
        const int qb = tg * SPS;
        const int kb = (16 + tg) * SPS;
        const int vb = (32 + tg) * SPS;
        float q[8];
        *(float4*)&q[0] = *(const float4*)&sP[qb + 8 * i];
        *(float4*)&q[4] = *(const float4*)&sP[qb + 8 * i + 4];
        float pr[8];
        float sum = 0.f;
        #pragma unroll
        for (int jj = 0; jj < 8; ++jj) {             // |s| <= 2.83 -> no max-sub
            const float4 k0 = *(const float4*)&sP[kb + 8 * jj];
            const float4 k1 = *(const float4*)&sP[kb + 8 * jj + 4];
            float s = q[0] * k0.x;
            s = fmaf(q[1], k0.y, s); s = fmaf(q[2], k0.z, s);
            s = fmaf(q[3], k0.w, s); s = fmaf(q[4], k1.x, s);
            s = fmaf(q[5], k1.y, s); s = fmaf(q[6], k1.z, s);
            s = fmaf(q[7], k1.w, s);
            pr[jj] = __expf(s * 0.35355339059327373f);
            sum += pr[jj];
        }
        const float rinv = 1.0f / sum;
        float o[8];
        #pragma unroll
        for (int w = 0; w < 8; ++w) o[w] = 0.f;
        #pragma unroll
        for (int jj = 0; jj < 8; ++jj) {
            const float4 v0 = *(const float4*)&sP[vb + 8 * jj];
            const float4 v1 = *(const float4*)&sP[vb + 8 * jj + 4];
            const float a = pr[jj] * rinv;
            o[0] = fmaf(a, v0.x, o[0]); o[1] = fmaf(a, v0.y, o[1]);
            o[2] = fmaf(a, v0.z, o[2]); o[3] = fmaf(a, v0.w, o[3]);
            o[4] = fmaf(a, v1.x, o[4]); o[5] = fmaf(a, v1.y, o[5]);
            o[6] = fmaf(a, v1.z, o[6]); o[7] = fmaf(a, v1.w, o[7]);
        }
        // scrambled row rho = i*2 + (tg>>3); col base 8*(tg&7); split-bf16
        u32 hh[4], ll[4];
        #pragma unroll
        for (int c = 0; c < 4; ++c)
            bfsplit2(o[2 * c], o[2 * c + 1], hh[c], ll[c]);
        const int so = (i * 2 + (tg >> 3)) * WRS + 8 * (tg & 7);
        *(uint4*)&sSh[so] = make_uint4(hh[0], hh[1], hh[2], hh[3]);
        *(uint4*)&sSl[so] = make_uint4(ll[0], ll[1], ll[2], ll[3]);
    }
    __syncthreads();                                 // B3: scr ready

    // ---- P3: y = scr @ Wo^T via MFMA; 1 ntile job per wave ----
    {
        const int arow = l15 * WRS + quad * 8;
        const bf16x8 sh0 = *(const bf16x8*)&sSh[arow];
        const bf16x8 sh1 = *(const bf16x8*)&sSh[arow + 32];
        const bf16x8 sl0 = *(const bf16x8*)&sSl[arow];
        const bf16x8 sl1 = *(const bf16x8*)&sSl[arow + 32];
        f32x4 acc = {0.f, 0.f, 0.f, 0.f};
        MFMA3(acc, sh0, sl0, obh0, obl0)
        MFMA3(acc, sh1, sl1, obh1, obl1)
        // store: lane holds y[rho][e] for 4 rho; rho -> global row
        const int e = wg * 16 + l15;
        #pragma unroll
        for (int r = 0; r < 4; ++r) {
            const int rho = quad * 4 + r;            // 0..15
            const int R   = (rho >> 1) * 64 + g16 * 2 + (rho & 1);
            outg[((size_t)(b * 512 + R)) * 64 + e] = acc[r];
        }
    }
}

extern "C" void kernel_launch(void* const* d_in, const int* in_sizes, int n_in,
                              void* d_out, int out_size, void* d_ws, size_t ws_size,
                              hipStream_t stream) {
    const float* x  = (const float*)d_in[0];
    const float* wq = (const float*)d_in[1];
    const float* wk = (const float*)d_in[2];
    const float* wv = (const float*)d_in[3];
    const float* wo = (const float*)d_in[4];
    const float* th = (const float*)d_in[5];
    float* out = (float*)d_out;
    // B=16, S=512: 16 batches x 32 sixteen-token groups = 512 blocks
    qattn_fused<<<dim3(512), dim3(256), 0, stream>>>(x, wq, wk, wv, wo, th, out);
}